// Round 6
// baseline (254.325 us; speedup 1.0000x reference)
//
#include <hip/hip_runtime.h>

// Chamfer loss: x,y (16, 4096, 3) fp32 -> scalar.
//
// Round-6: algorithmic change. Brute force (268M pairs) plateaued at
// part ~34 us vs 44 us fixed harness ws-poison fill. Points are N(0,1);
// expected NN dist^2 ~ 0.009 -> |dz| cutoff ~ 0.1. Bucket both clouds by
// z (64 buckets, width 0.125) and scan buckets outward until the z-gap
// provably beats the wave-worst current min: ~300 candidates/x instead of
// 4096, exact result (excluded y have true d >= gap^2 > best*1.0001+1e-6;
// surviving candidates use the same fmaf chain as rounds 1-5).
//   t = fma(-x0,2y0, fma(-x1,2y1, fma(-x2,2y2, ||y||^2))),  d = ||x||^2 + t
// Sum over x is permutation-invariant -> x is bucket-reordered with no
// inverse map; lanes get z-sorted x -> wave-uniform scan windows.
// 2 dispatches: K1 buckets x,y + zeroes out; K2 scans + atomicAdds sums.
//
// ws: [0,1.5MB) ybuf (16x4096 float4: 2y0,2y1,2y2,||y||^2, bucket-major)
//     [1.5,2.5MB) xbuf (16x4096 float4: x0,x1,x2,||x||^2, bucket-major)
//     [2.5MB,+4KB) yoffs (16 x 65 u32)

constexpr int NPTS   = 4096;
constexpr int NBATCH = 16;
constexpr int BLOCK  = 256;
constexpr int NBKT   = 64;
constexpr float ZLO  = -4.0f;
constexpr float BW   = 0.125f;   // bucket width (exact in fp32)
constexpr float IBW  = 8.0f;

__device__ __forceinline__ int zbucket(float z) {
    int k = (int)floorf((z - ZLO) * IBW);
    return min(NBKT - 1, max(0, k));
}

// ---------------- K1: bucket y (packed) and x, zero out --------------------

__global__ __launch_bounds__(BLOCK) void chamfer_bucket_kernel(
    const float* __restrict__ x, const float* __restrict__ y,
    float4* __restrict__ ybuf, float4* __restrict__ xbuf,
    unsigned int* __restrict__ yoffs, float* __restrict__ out)
{
    __shared__ unsigned int hist[NBKT], curs[NBKT], offs[NBKT + 1];
    const int b   = blockIdx.x;
    const int tid = threadIdx.x;
    if (b == 0 && tid == 0) out[0] = 0.0f;

    // ---- y histogram ----
    if (tid < NBKT) hist[tid] = 0;
    __syncthreads();
    for (int i = tid; i < NPTS; i += BLOCK)
        atomicAdd(&hist[zbucket(y[((size_t)b * NPTS + i) * 3 + 2])], 1u);
    __syncthreads();
    if (tid == 0) {
        unsigned int run = 0;
        for (int k = 0; k < NBKT; ++k) { offs[k] = run; curs[k] = run; run += hist[k]; }
        offs[NBKT] = run;               // == NPTS
    }
    __syncthreads();
    // ---- y scatter, packed (2y0, 2y1, 2y2, ||y||^2) ----
    for (int i = tid; i < NPTS; i += BLOCK) {
        const float* yp = y + ((size_t)b * NPTS + i) * 3;
        const float y0 = yp[0], y1 = yp[1], y2 = yp[2];
        const unsigned int pos = atomicAdd(&curs[zbucket(y2)], 1u);
        ybuf[(size_t)b * NPTS + pos] = make_float4(
            2.0f * y0, 2.0f * y1, 2.0f * y2,
            fmaf(y2, y2, fmaf(y1, y1, y0 * y0)));
    }
    __syncthreads();
    if (tid <= NBKT) yoffs[b * (NBKT + 1) + tid] = offs[tid];

    // ---- x histogram (reuse hist/curs) ----
    if (tid < NBKT) hist[tid] = 0;
    __syncthreads();
    for (int i = tid; i < NPTS; i += BLOCK)
        atomicAdd(&hist[zbucket(x[((size_t)b * NPTS + i) * 3 + 2])], 1u);
    __syncthreads();
    if (tid == 0) {
        unsigned int run = 0;
        for (int k = 0; k < NBKT; ++k) { curs[k] = run; run += hist[k]; }
    }
    __syncthreads();
    // ---- x scatter (x0, x1, x2, ||x||^2) ----
    for (int i = tid; i < NPTS; i += BLOCK) {
        const float* xp = x + ((size_t)b * NPTS + i) * 3;
        const float x0 = xp[0], x1 = xp[1], x2 = xp[2];
        const unsigned int pos = atomicAdd(&curs[zbucket(x2)], 1u);
        xbuf[(size_t)b * NPTS + pos] = make_float4(
            x0, x1, x2, fmaf(x2, x2, fmaf(x1, x1, x0 * x0)));
    }
}

// ---------------- K2: per-x NN via outward bucket sweep --------------------

__global__ __launch_bounds__(BLOCK) void chamfer_nn_kernel(
    const float4* __restrict__ xbuf, const float4* __restrict__ ybuf,
    const unsigned int* __restrict__ yoffs, float* __restrict__ out)
{
    __shared__ unsigned int off[NBKT + 1];
    __shared__ float swsum[BLOCK / 64];
    const int tid = threadIdx.x;
    const int b   = blockIdx.x >> 4;         // 16 blocks per batch
    if (tid <= NBKT) off[tid] = yoffs[b * (NBKT + 1) + tid];
    __syncthreads();

    const int idx  = blockIdx.x * BLOCK + tid;
    const float4 X = xbuf[idx];
    const float  z = X.z;
    const int    k = zbucket(z);

    // Wave extremes (lanes hold z-sorted consecutive x -> tight windows).
    int   kmn = k, kmx = k;
    float zmn = z, zmx = z;
    #pragma unroll
    for (int m = 1; m < 64; m <<= 1) {
        kmn = min(kmn, __shfl_xor(kmn, m, 64));
        kmx = max(kmx, __shfl_xor(kmx, m, 64));
        zmn = fminf(zmn, __shfl_xor(zmn, m, 64));
        zmx = fmaxf(zmx, __shfl_xor(zmx, m, 64));
    }

    const float4* yb = ybuf + (size_t)b * NPTS;
    float best = 1e30f;

    auto scan = [&](int klo, int khi) {
        const unsigned int je = off[khi + 1];
        unsigned int j = off[klo];
        for (; j + 4 <= je; j += 4) {        // 4 loads in flight
            const float4 Y0 = yb[j], Y1 = yb[j + 1];
            const float4 Y2 = yb[j + 2], Y3 = yb[j + 3];
            const float t0 = fmaf(-X.x, Y0.x, fmaf(-X.y, Y0.y, fmaf(-X.z, Y0.z, Y0.w)));
            const float t1 = fmaf(-X.x, Y1.x, fmaf(-X.y, Y1.y, fmaf(-X.z, Y1.z, Y1.w)));
            const float t2 = fmaf(-X.x, Y2.x, fmaf(-X.y, Y2.y, fmaf(-X.z, Y2.z, Y2.w)));
            const float t3 = fmaf(-X.x, Y3.x, fmaf(-X.y, Y3.y, fmaf(-X.z, Y3.z, Y3.w)));
            best = fminf(fminf(fminf(t0, t1), fminf(t2, t3)), best);
        }
        for (; j < je; ++j) {
            const float4 Y0 = yb[j];
            best = fminf(best,
                fmaf(-X.x, Y0.x, fmaf(-X.y, Y0.y, fmaf(-X.z, Y0.z, Y0.w))));
        }
    };

    int lo = kmn, hi = kmx;
    scan(lo, hi);
    for (;;) {
        float worst = X.w + best;            // current distance, this lane
        #pragma unroll
        for (int m = 1; m < 64; m <<= 1)
            worst = fmaxf(worst, __shfl_xor(worst, m, 64));
        const float thr = worst * 1.0001f + 1e-6f;
        // gap from wave z-extremes to the unscanned region's nearest edge
        const float Lg = (lo == 0)        ? 1e18f : zmn - (ZLO + lo * BW);
        const float Hg = (hi == NBKT - 1) ? 1e18f : (ZLO + (hi + 1) * BW) - zmx;
        const bool okL = Lg * Lg > thr;
        const bool okH = Hg * Hg > thr;
        if (okL && okH) break;
        if (!okL && (okH || Lg <= Hg)) { --lo; scan(lo, lo); }
        else                           { ++hi; scan(hi, hi); }
    }

    const float d = fmaxf(X.w + best, 0.0f);

    float s = d;
    for (int o = 32; o > 0; o >>= 1) s += __shfl_down(s, o, 64);
    if ((tid & 63) == 0) swsum[tid >> 6] = s;
    __syncthreads();
    if (tid == 0) {
        float t = 0.0f;
        #pragma unroll
        for (int w = 0; w < BLOCK / 64; ++w) t += swsum[w];
        atomicAdd(out, t * (1.0f / NPTS));
    }
}

// ---------------- fallback: proven atomic path (tiny ws) -------------------

constexpr int XPT    = 8;
constexpr int XCHUNK = BLOCK * XPT;
constexpr int NXC    = NPTS / XCHUNK;

__global__ __launch_bounds__(BLOCK) void chamfer_min_atomic_kernel(
    const float* __restrict__ x, const float* __restrict__ y,
    unsigned int* __restrict__ ws_min)
{
    constexpr int YTILE = 256;
    constexpr int FNYC  = NPTS / YTILE;
    __shared__ float4 sy[YTILE];

    const int b      = blockIdx.x / (NXC * FNYC);
    const int xchunk = (blockIdx.x / FNYC) % NXC;
    const int ychunk = blockIdx.x % FNYC;

    {
        const float* yp = y + ((size_t)b * NPTS + ychunk * YTILE + threadIdx.x) * 3;
        const float y0 = yp[0], y1 = yp[1], y2 = yp[2];
        sy[threadIdx.x] = make_float4(2.0f * y0, 2.0f * y1, 2.0f * y2,
                                      fmaf(y2, y2, fmaf(y1, y1, y0 * y0)));
    }

    const int xbase = xchunk * XCHUNK + threadIdx.x * XPT;
    const float4* xp4 = (const float4*)(x + ((size_t)b * NPTS + xbase) * 3);
    float xf[24];
    #pragma unroll
    for (int q = 0; q < 6; ++q) {
        const float4 a = xp4[q];
        xf[4 * q + 0] = a.x; xf[4 * q + 1] = a.y;
        xf[4 * q + 2] = a.z; xf[4 * q + 3] = a.w;
    }

    __syncthreads();

    float m[XPT];
    #pragma unroll
    for (int i = 0; i < XPT; ++i) m[i] = 3.4e38f;

    #pragma unroll 1
    for (int j = 0; j < YTILE; j += 2) {
        const float4 Y0 = sy[j];
        const float4 Y1 = sy[j + 1];
        #pragma unroll
        for (int i = 0; i < XPT; ++i) {
            const float t0 = fmaf(-xf[3 * i + 0], Y0.x,
                             fmaf(-xf[3 * i + 1], Y0.y,
                             fmaf(-xf[3 * i + 2], Y0.z, Y0.w)));
            const float t1 = fmaf(-xf[3 * i + 0], Y1.x,
                             fmaf(-xf[3 * i + 1], Y1.y,
                             fmaf(-xf[3 * i + 2], Y1.z, Y1.w)));
            m[i] = fminf(m[i], fminf(t0, t1));
        }
    }

    unsigned int* wm = ws_min + (size_t)b * NPTS + xbase;
    #pragma unroll
    for (int i = 0; i < XPT; ++i) {
        const float x2 = fmaf(xf[3 * i + 2], xf[3 * i + 2],
                         fmaf(xf[3 * i + 1], xf[3 * i + 1],
                              xf[3 * i + 0] * xf[3 * i + 0]));
        const float d = fmaxf(x2 + m[i], 0.0f);
        atomicMin(&wm[i], __float_as_uint(d));
    }
}

__global__ __launch_bounds__(BLOCK) void chamfer_sum_kernel(
    const unsigned int* __restrict__ ws_min, float* __restrict__ out)
{
    __shared__ float swsum[BLOCK / 64];
    const int total = NBATCH * NPTS;
    float s = 0.f;
    for (int i = blockIdx.x * BLOCK + threadIdx.x; i < total;
         i += gridDim.x * BLOCK)
        s += __uint_as_float(ws_min[i]);

    for (int off = 32; off > 0; off >>= 1)
        s += __shfl_down(s, off, 64);
    const int wave = threadIdx.x >> 6;
    if ((threadIdx.x & 63) == 0) swsum[wave] = s;
    __syncthreads();
    if (threadIdx.x == 0) {
        float t = 0.f;
        #pragma unroll
        for (int w = 0; w < BLOCK / 64; ++w) t += swsum[w];
        atomicAdd(out, t * (1.0f / NPTS));
    }
}

// ---------------- host ------------------------------------------------------

extern "C" void kernel_launch(void* const* d_in, const int* in_sizes, int n_in,
                              void* d_out, int out_size, void* d_ws, size_t ws_size,
                              hipStream_t stream) {
    const float* x = (const float*)d_in[0];
    const float* y = (const float*)d_in[1];
    float* out = (float*)d_out;

    const size_t YBUF_OFF  = 0;
    const size_t XBUF_OFF  = (size_t)3 * 512 * 1024;         // 1.5 MB
    const size_t YOFFS_OFF = (size_t)5 * 512 * 1024;         // 2.5 MB
    const size_t NEED      = YOFFS_OFF + (size_t)NBATCH * (NBKT + 1) * 4 + 4096;

    if (ws_size >= NEED) {
        float4* ybuf = (float4*)((char*)d_ws + YBUF_OFF);
        float4* xbuf = (float4*)((char*)d_ws + XBUF_OFF);
        unsigned int* yoffs = (unsigned int*)((char*)d_ws + YOFFS_OFF);
        chamfer_bucket_kernel<<<NBATCH, BLOCK, 0, stream>>>(
            x, y, ybuf, xbuf, yoffs, out);
        chamfer_nn_kernel<<<NBATCH * NPTS / BLOCK, BLOCK, 0, stream>>>(
            xbuf, ybuf, yoffs, out);
    } else {
        unsigned int* ws_min = (unsigned int*)d_ws;
        hipMemsetAsync(out, 0, sizeof(float), stream);
        hipMemsetAsync(ws_min, 0xFF, (size_t)NBATCH * NPTS * sizeof(unsigned int),
                       stream);
        chamfer_min_atomic_kernel<<<NBATCH * NXC * 16, BLOCK, 0, stream>>>(
            x, y, ws_min);
        chamfer_sum_kernel<<<64, BLOCK, 0, stream>>>(ws_min, out);
    }
}

// Round 7
// 86.781 us; speedup vs baseline: 2.9307x; 2.9307x over previous
//
#include <hip/hip_runtime.h>

// Chamfer loss: x,y (16, 4096, 3) fp32 -> scalar.
//
// d(x,y) = ||x||^2 + (||y||^2 - 2 x.y); min over y only needs
//   t = fma(-x0,2y0, fma(-x1,2y1, fma(-x2,2y2, ||y||^2)))
// with (2y0,2y1,2y2,||y||^2) packed per y-point at LDS-staging time.
// 3 FMA + 0.5 min3 per pair -> ~12 us VALU-issue floor for 268M pairs.
//
// Round-7: consolidation on the proven round-2 champion (85.3 us).
//  - R3 (XPT=16), R4 (SGPR-y), R5 (8 waves/SIMD), R6 (z-bucket pruning) all
//    regressed. R6's counters showed why pruning fails here: termination is
//    coupled to the WAVE-MAX NN distance (heavy tail -> whole wave rescans)
//    and 1 wave/SIMD exposes every load's latency.
//  - Exact R2 structure: XPT=8, NYC=32 (y-tile 128, 2 KB LDS), 1024 blocks,
//    __launch_bounds__(256,4).
//  - Change 1: inner loop 4y -> 8y per hw iteration (8 ds_read_b128 in
//    flight; ~74 live VGPRs, under the 128 cap).
//  - Change 2: out zeroed by part block 0 (drops the memset dispatch from
//    the timed loop; reduce runs strictly after part on the stream).

constexpr int NPTS   = 4096;
constexpr int NBATCH = 16;
constexpr int BLOCK  = 256;
constexpr int XPT    = 8;                    // x-points per thread
constexpr int XCHUNK = BLOCK * XPT;          // 2048
constexpr int NXC    = NPTS / XCHUNK;        // 2
constexpr int NYC    = 32;                   // y-chunks
constexpr int YT     = NPTS / NYC;           // 128 y-points per block (2 KB LDS)

// ---------------- pass 1: partial mins (proven R2 shape, deeper y-pipe) ----

__global__ __launch_bounds__(BLOCK, 4) void chamfer_part_kernel(
    const float* __restrict__ x, const float* __restrict__ y,
    float* __restrict__ ws, float* __restrict__ out)
{
    __shared__ float4 sy[YT];                // (2y0, 2y1, 2y2, ||y||^2)

    if (blockIdx.x == 0 && threadIdx.x == 0) out[0] = 0.0f;

    const int b      = blockIdx.x / (NXC * NYC);
    const int xchunk = (blockIdx.x / NYC) % NXC;
    const int ychunk = blockIdx.x % NYC;

    for (int i = threadIdx.x; i < YT; i += BLOCK) {
        const float* yp = y + ((size_t)b * NPTS + ychunk * YT + i) * 3;
        const float y0 = yp[0], y1 = yp[1], y2 = yp[2];
        sy[i] = make_float4(2.0f * y0, 2.0f * y1, 2.0f * y2,
                            fmaf(y2, y2, fmaf(y1, y1, y0 * y0)));
    }

    // This thread's 8 consecutive x-points (24 floats = 6 float4).
    const int xbase = xchunk * XCHUNK + threadIdx.x * XPT;
    const float4* xp4 = (const float4*)(x + ((size_t)b * NPTS + xbase) * 3);
    const float4 a0 = xp4[0], a1 = xp4[1], a2 = xp4[2];
    const float4 a3 = xp4[3], a4 = xp4[4], a5 = xp4[5];
    const float xa[XPT][3] = {
        {a0.x, a0.y, a0.z}, {a0.w, a1.x, a1.y},
        {a1.z, a1.w, a2.x}, {a2.y, a2.z, a2.w},
        {a3.x, a3.y, a3.z}, {a3.w, a4.x, a4.y},
        {a4.z, a4.w, a5.x}, {a5.y, a5.z, a5.w}};

    float x2s[XPT];
    #pragma unroll
    for (int i = 0; i < XPT; ++i)
        x2s[i] = fmaf(xa[i][2], xa[i][2],
                 fmaf(xa[i][1], xa[i][1], xa[i][0] * xa[i][0]));

    __syncthreads();

    float m[XPT];
    #pragma unroll
    for (int i = 0; i < XPT; ++i) m[i] = 3.4e38f;

    #pragma unroll 2
    for (int j = 0; j < YT; j += 4) {        // 8 y in flight per hw iter
        const float4 Y0 = sy[j + 0];
        const float4 Y1 = sy[j + 1];
        const float4 Y2 = sy[j + 2];
        const float4 Y3 = sy[j + 3];
        #pragma unroll
        for (int i = 0; i < XPT; ++i) {
            const float t0 = fmaf(-xa[i][0], Y0.x,
                             fmaf(-xa[i][1], Y0.y,
                             fmaf(-xa[i][2], Y0.z, Y0.w)));
            const float t1 = fmaf(-xa[i][0], Y1.x,
                             fmaf(-xa[i][1], Y1.y,
                             fmaf(-xa[i][2], Y1.z, Y1.w)));
            const float t2 = fmaf(-xa[i][0], Y2.x,
                             fmaf(-xa[i][1], Y2.y,
                             fmaf(-xa[i][2], Y2.z, Y2.w)));
            const float t3 = fmaf(-xa[i][0], Y3.x,
                             fmaf(-xa[i][1], Y3.y,
                             fmaf(-xa[i][2], Y3.z, Y3.w)));
            m[i] = fminf(fminf(fminf(t0, t1), fminf(t2, t3)), m[i]);
        }
    }

    // d = max(||x||^2 + min_t, 0), stored ws[b][ychunk][xpoint] coalesced.
    float* wp = ws + ((size_t)b * NYC + ychunk) * NPTS + xbase;
    #pragma unroll
    for (int i = 0; i < XPT; i += 4) {
        float4 o;
        float* oc = (float*)&o;
        #pragma unroll
        for (int k = 0; k < 4; ++k)
            oc[k] = fmaxf(x2s[i + k] + m[i + k], 0.0f);
        ((float4*)wp)[i / 4] = o;
    }
}

// ---------------- pass 2: min over ychunks, then sum -----------------------

__global__ __launch_bounds__(BLOCK) void chamfer_reduce_kernel(
    const float* __restrict__ ws, float* __restrict__ out)
{
    __shared__ float swsum[BLOCK / 64];
    const int idx = blockIdx.x * BLOCK + threadIdx.x;   // one x-point each
    const int b   = idx / NPTS;
    const int xp  = idx % NPTS;

    const float* p = ws + (size_t)b * NYC * NPTS + xp;
    float mn = 3.4e38f;
    #pragma unroll 8
    for (int yc = 0; yc < NYC; ++yc)
        mn = fminf(mn, p[(size_t)yc * NPTS]);

    float s = mn;
    for (int off = 32; off > 0; off >>= 1)
        s += __shfl_down(s, off, 64);
    const int wave = threadIdx.x >> 6;
    if ((threadIdx.x & 63) == 0) swsum[wave] = s;
    __syncthreads();
    if (threadIdx.x == 0) {
        float t = 0.f;
        #pragma unroll
        for (int w = 0; w < BLOCK / 64; ++w) t += swsum[w];
        atomicAdd(out, t * (1.0f / NPTS));
    }
}

// ---------------- fallback: atomic path (tiny ws) --------------------------

__global__ __launch_bounds__(BLOCK) void chamfer_min_atomic_kernel(
    const float* __restrict__ x, const float* __restrict__ y,
    unsigned int* __restrict__ ws_min)
{
    constexpr int YTILE = 256;
    constexpr int FNYC  = NPTS / YTILE;
    __shared__ float4 sy[YTILE];

    const int b      = blockIdx.x / (NXC * FNYC);
    const int xchunk = (blockIdx.x / FNYC) % NXC;
    const int ychunk = blockIdx.x % FNYC;

    {
        const float* yp = y + ((size_t)b * NPTS + ychunk * YTILE + threadIdx.x) * 3;
        const float y0 = yp[0], y1 = yp[1], y2 = yp[2];
        sy[threadIdx.x] = make_float4(2.0f * y0, 2.0f * y1, 2.0f * y2,
                                      fmaf(y2, y2, fmaf(y1, y1, y0 * y0)));
    }

    const int xbase = xchunk * XCHUNK + threadIdx.x * XPT;
    const float4* xp4 = (const float4*)(x + ((size_t)b * NPTS + xbase) * 3);
    const float4 a0 = xp4[0], a1 = xp4[1], a2 = xp4[2];
    const float4 a3 = xp4[3], a4 = xp4[4], a5 = xp4[5];
    const float xa[XPT][3] = {
        {a0.x, a0.y, a0.z}, {a0.w, a1.x, a1.y},
        {a1.z, a1.w, a2.x}, {a2.y, a2.z, a2.w},
        {a3.x, a3.y, a3.z}, {a3.w, a4.x, a4.y},
        {a4.z, a4.w, a5.x}, {a5.y, a5.z, a5.w}};

    float x2s[XPT];
    #pragma unroll
    for (int i = 0; i < XPT; ++i)
        x2s[i] = fmaf(xa[i][2], xa[i][2],
                 fmaf(xa[i][1], xa[i][1], xa[i][0] * xa[i][0]));

    __syncthreads();

    float m[XPT];
    #pragma unroll
    for (int i = 0; i < XPT; ++i) m[i] = 3.4e38f;

    #pragma unroll 2
    for (int j = 0; j < YTILE; j += 2) {
        const float4 Y0 = sy[j];
        const float4 Y1 = sy[j + 1];
        #pragma unroll
        for (int i = 0; i < XPT; ++i) {
            const float t0 = fmaf(-xa[i][0], Y0.x,
                             fmaf(-xa[i][1], Y0.y,
                             fmaf(-xa[i][2], Y0.z, Y0.w)));
            const float t1 = fmaf(-xa[i][0], Y1.x,
                             fmaf(-xa[i][1], Y1.y,
                             fmaf(-xa[i][2], Y1.z, Y1.w)));
            m[i] = fminf(m[i], fminf(t0, t1));
        }
    }

    unsigned int* wm = ws_min + (size_t)b * NPTS + xbase;
    #pragma unroll
    for (int i = 0; i < XPT; ++i) {
        const float d = fmaxf(x2s[i] + m[i], 0.0f);
        atomicMin(&wm[i], __float_as_uint(d));
    }
}

__global__ __launch_bounds__(BLOCK) void chamfer_sum_kernel(
    const unsigned int* __restrict__ ws_min, float* __restrict__ out)
{
    __shared__ float swsum[BLOCK / 64];
    const int total = NBATCH * NPTS;
    float s = 0.f;
    for (int i = blockIdx.x * BLOCK + threadIdx.x; i < total;
         i += gridDim.x * BLOCK)
        s += __uint_as_float(ws_min[i]);

    for (int off = 32; off > 0; off >>= 1)
        s += __shfl_down(s, off, 64);
    const int wave = threadIdx.x >> 6;
    if ((threadIdx.x & 63) == 0) swsum[wave] = s;
    __syncthreads();
    if (threadIdx.x == 0) {
        float t = 0.f;
        #pragma unroll
        for (int w = 0; w < BLOCK / 64; ++w) t += swsum[w];
        atomicAdd(out, t * (1.0f / NPTS));
    }
}

// ---------------- host ------------------------------------------------------

extern "C" void kernel_launch(void* const* d_in, const int* in_sizes, int n_in,
                              void* d_out, int out_size, void* d_ws, size_t ws_size,
                              hipStream_t stream) {
    const float* x = (const float*)d_in[0];
    const float* y = (const float*)d_in[1];
    float* out = (float*)d_out;

    const size_t need = (size_t)NBATCH * NYC * NPTS * sizeof(float);   // 8 MB

    if (ws_size >= need) {
        float* ws = (float*)d_ws;
        chamfer_part_kernel<<<NBATCH * NXC * NYC, BLOCK, 0, stream>>>(
            x, y, ws, out);
        chamfer_reduce_kernel<<<NBATCH * NPTS / BLOCK, BLOCK, 0, stream>>>(
            ws, out);
    } else {
        unsigned int* ws_min = (unsigned int*)d_ws;
        hipMemsetAsync(out, 0, sizeof(float), stream);
        hipMemsetAsync(ws_min, 0xFF, (size_t)NBATCH * NPTS * sizeof(unsigned int),
                       stream);
        chamfer_min_atomic_kernel<<<NBATCH * NXC * 16, BLOCK, 0, stream>>>(
            x, y, ws_min);
        chamfer_sum_kernel<<<64, BLOCK, 0, stream>>>(ws_min, out);
    }
}

// Round 8
// 85.313 us; speedup vs baseline: 2.9811x; 1.0172x over previous
//
#include <hip/hip_runtime.h>

// Chamfer loss: x,y (16, 4096, 3) fp32 -> scalar.
//
// d(x,y) = ||x||^2 + (||y||^2 - 2 x.y); min over y only needs
//   t = fma(-x0,2y0, fma(-x1,2y1, fma(-x2,2y2, ||y||^2)))
//
// Round-8: packed-fp32 inner loop. Evidence: R5/R7 occupancy & pipelining
// changes were neutral; part time has tracked emitted instruction count
// across all rounds (R1 7/pair->43.6us, R2 3.75/pair->~35us) -> the loop is
// issue-limited. CDNA2+ has full-rate packed fp32 (v_pk_fma_f32), which the
// scalar loop never uses. Process TWO y per packed op:
//   - LDS stores y pair-interleaved: syp[2p]   = (2y0a,2y0b, 2y1a,2y1b)
//                                    syp[2p+1] = (2y2a,2y2b,  na,  nb)
//     so two ds_read_b128 give float2 operands by sub-register aliasing.
//   - x kept as pre-negated float2 splats; m accumulated as float2.
//   - body per 2 pairs: 3 v_pk_fma + packed min -> 2.0-2.5 instr/pair
//     (vs 3.75 scalar). -ffp-contract=fast (HIP default) forms the fmas.
// Rest is the proven R2 shape: XPT=8, YT=128, NYC=32, 1024 blocks,
// __launch_bounds__(256,4). out zeroed by part block 0 (2 dispatches).

typedef float v2f __attribute__((ext_vector_type(2)));

__device__ __forceinline__ v2f vmin2(v2f a, v2f b) {
#if __has_builtin(__builtin_elementwise_min)
    return __builtin_elementwise_min(a, b);
#else
    v2f r; r.x = fminf(a.x, b.x); r.y = fminf(a.y, b.y); return r;
#endif
}

constexpr int NPTS   = 4096;
constexpr int NBATCH = 16;
constexpr int BLOCK  = 256;
constexpr int XPT    = 8;                    // x-points per thread
constexpr int XCHUNK = BLOCK * XPT;          // 2048
constexpr int NXC    = NPTS / XCHUNK;        // 2
constexpr int NYC    = 32;                   // y-chunks
constexpr int YT     = NPTS / NYC;           // 128 y-points per block
constexpr int YPAIRS = YT / 2;               // 64 pairs

// ---------------- pass 1: partial mins, packed-fp32 inner loop -------------

__global__ __launch_bounds__(BLOCK, 4) void chamfer_part_kernel(
    const float* __restrict__ x, const float* __restrict__ y,
    float* __restrict__ ws, float* __restrict__ out)
{
    __shared__ float4 syp[YT];               // 2 float4 per y-pair (2 KB)

    if (blockIdx.x == 0 && threadIdx.x == 0) out[0] = 0.0f;

    const int b      = blockIdx.x / (NXC * NYC);
    const int xchunk = (blockIdx.x / NYC) % NXC;
    const int ychunk = blockIdx.x % NYC;

    // Stage 64 y-pairs, pair-interleaved for packed math.
    for (int p = threadIdx.x; p < YPAIRS; p += BLOCK) {
        const float* yp = y + ((size_t)b * NPTS + ychunk * YT + 2 * p) * 3;
        const float a0 = yp[0], a1 = yp[1], a2 = yp[2];
        const float b0 = yp[3], b1 = yp[4], b2 = yp[5];
        syp[2 * p]     = make_float4(2.0f * a0, 2.0f * b0, 2.0f * a1, 2.0f * b1);
        syp[2 * p + 1] = make_float4(2.0f * a2, 2.0f * b2,
                                     fmaf(a2, a2, fmaf(a1, a1, a0 * a0)),
                                     fmaf(b2, b2, fmaf(b1, b1, b0 * b0)));
    }

    // This thread's 8 consecutive x-points (24 floats = 6 float4),
    // stored as NEGATED float2 splats (packed-fma operand form).
    const int xbase = xchunk * XCHUNK + threadIdx.x * XPT;
    const float4* xp4 = (const float4*)(x + ((size_t)b * NPTS + xbase) * 3);
    const float4 a0 = xp4[0], a1 = xp4[1], a2 = xp4[2];
    const float4 a3 = xp4[3], a4 = xp4[4], a5 = xp4[5];
    const float xa[XPT][3] = {
        {a0.x, a0.y, a0.z}, {a0.w, a1.x, a1.y},
        {a1.z, a1.w, a2.x}, {a2.y, a2.z, a2.w},
        {a3.x, a3.y, a3.z}, {a3.w, a4.x, a4.y},
        {a4.z, a4.w, a5.x}, {a5.y, a5.z, a5.w}};
    v2f xs[XPT][3];
    #pragma unroll
    for (int i = 0; i < XPT; ++i)
        #pragma unroll
        for (int c = 0; c < 3; ++c) {
            const float nx = -xa[i][c];
            xs[i][c].x = nx; xs[i][c].y = nx;
        }

    __syncthreads();

    v2f m2[XPT];
    #pragma unroll
    for (int i = 0; i < XPT; ++i) { m2[i].x = 3.4e38f; m2[i].y = 3.4e38f; }

    #pragma unroll 2
    for (int p = 0; p < YPAIRS; ++p) {
        const float4 Q0 = syp[2 * p];
        const float4 Q1 = syp[2 * p + 1];
        v2f c0, c1, c2, nn;                  // sub-register views of Q0/Q1
        c0.x = Q0.x; c0.y = Q0.y;  c1.x = Q0.z; c1.y = Q0.w;
        c2.x = Q1.x; c2.y = Q1.y;  nn.x = Q1.z; nn.y = Q1.w;
        #pragma unroll
        for (int i = 0; i < XPT; ++i) {
            // contract=fast -> 3x v_pk_fma_f32: t = -x0*2y0 -x1*2y1 -x2*2y2 + n
            const v2f t = c0 * xs[i][0] + (c1 * xs[i][1] + (c2 * xs[i][2] + nn));
            m2[i] = vmin2(m2[i], t);
        }
    }

    // d = max(||x||^2 + min_t, 0); ||x||^2 recomputed from the splats.
    float* wp = ws + ((size_t)b * NYC + ychunk) * NPTS + xbase;
    #pragma unroll
    for (int i = 0; i < XPT; i += 4) {
        float4 o;
        float* oc = (float*)&o;
        #pragma unroll
        for (int k = 0; k < 4; ++k) {
            const int q = i + k;
            const float x2 = fmaf(xs[q][2].x, xs[q][2].x,
                             fmaf(xs[q][1].x, xs[q][1].x,
                                  xs[q][0].x * xs[q][0].x));
            oc[k] = fmaxf(x2 + fminf(m2[q].x, m2[q].y), 0.0f);
        }
        ((float4*)wp)[i / 4] = o;
    }
}

// ---------------- pass 2: min over ychunks, then sum -----------------------

__global__ __launch_bounds__(BLOCK) void chamfer_reduce_kernel(
    const float* __restrict__ ws, float* __restrict__ out)
{
    __shared__ float swsum[BLOCK / 64];
    const int idx = blockIdx.x * BLOCK + threadIdx.x;   // one x-point each
    const int b   = idx / NPTS;
    const int xp  = idx % NPTS;

    const float* p = ws + (size_t)b * NYC * NPTS + xp;
    float mn = 3.4e38f;
    #pragma unroll 8
    for (int yc = 0; yc < NYC; ++yc)
        mn = fminf(mn, p[(size_t)yc * NPTS]);

    float s = mn;
    for (int off = 32; off > 0; off >>= 1)
        s += __shfl_down(s, off, 64);
    const int wave = threadIdx.x >> 6;
    if ((threadIdx.x & 63) == 0) swsum[wave] = s;
    __syncthreads();
    if (threadIdx.x == 0) {
        float t = 0.f;
        #pragma unroll
        for (int w = 0; w < BLOCK / 64; ++w) t += swsum[w];
        atomicAdd(out, t * (1.0f / NPTS));
    }
}

// ---------------- fallback: atomic path (tiny ws) --------------------------

__global__ __launch_bounds__(BLOCK) void chamfer_min_atomic_kernel(
    const float* __restrict__ x, const float* __restrict__ y,
    unsigned int* __restrict__ ws_min)
{
    constexpr int YTILE = 256;
    constexpr int FNYC  = NPTS / YTILE;
    __shared__ float4 sy[YTILE];

    const int b      = blockIdx.x / (NXC * FNYC);
    const int xchunk = (blockIdx.x / FNYC) % NXC;
    const int ychunk = blockIdx.x % FNYC;

    {
        const float* yp = y + ((size_t)b * NPTS + ychunk * YTILE + threadIdx.x) * 3;
        const float y0 = yp[0], y1 = yp[1], y2 = yp[2];
        sy[threadIdx.x] = make_float4(2.0f * y0, 2.0f * y1, 2.0f * y2,
                                      fmaf(y2, y2, fmaf(y1, y1, y0 * y0)));
    }

    const int xbase = xchunk * XCHUNK + threadIdx.x * XPT;
    const float4* xp4 = (const float4*)(x + ((size_t)b * NPTS + xbase) * 3);
    const float4 a0 = xp4[0], a1 = xp4[1], a2 = xp4[2];
    const float4 a3 = xp4[3], a4 = xp4[4], a5 = xp4[5];
    const float xa[XPT][3] = {
        {a0.x, a0.y, a0.z}, {a0.w, a1.x, a1.y},
        {a1.z, a1.w, a2.x}, {a2.y, a2.z, a2.w},
        {a3.x, a3.y, a3.z}, {a3.w, a4.x, a4.y},
        {a4.z, a4.w, a5.x}, {a5.y, a5.z, a5.w}};

    float x2s[XPT];
    #pragma unroll
    for (int i = 0; i < XPT; ++i)
        x2s[i] = fmaf(xa[i][2], xa[i][2],
                 fmaf(xa[i][1], xa[i][1], xa[i][0] * xa[i][0]));

    __syncthreads();

    float m[XPT];
    #pragma unroll
    for (int i = 0; i < XPT; ++i) m[i] = 3.4e38f;

    #pragma unroll 2
    for (int j = 0; j < YTILE; j += 2) {
        const float4 Y0 = sy[j];
        const float4 Y1 = sy[j + 1];
        #pragma unroll
        for (int i = 0; i < XPT; ++i) {
            const float t0 = fmaf(-xa[i][0], Y0.x,
                             fmaf(-xa[i][1], Y0.y,
                             fmaf(-xa[i][2], Y0.z, Y0.w)));
            const float t1 = fmaf(-xa[i][0], Y1.x,
                             fmaf(-xa[i][1], Y1.y,
                             fmaf(-xa[i][2], Y1.z, Y1.w)));
            m[i] = fminf(m[i], fminf(t0, t1));
        }
    }

    unsigned int* wm = ws_min + (size_t)b * NPTS + xbase;
    #pragma unroll
    for (int i = 0; i < XPT; ++i) {
        const float d = fmaxf(x2s[i] + m[i], 0.0f);
        atomicMin(&wm[i], __float_as_uint(d));
    }
}

__global__ __launch_bounds__(BLOCK) void chamfer_sum_kernel(
    const unsigned int* __restrict__ ws_min, float* __restrict__ out)
{
    __shared__ float swsum[BLOCK / 64];
    const int total = NBATCH * NPTS;
    float s = 0.f;
    for (int i = blockIdx.x * BLOCK + threadIdx.x; i < total;
         i += gridDim.x * BLOCK)
        s += __uint_as_float(ws_min[i]);

    for (int off = 32; off > 0; off >>= 1)
        s += __shfl_down(s, off, 64);
    const int wave = threadIdx.x >> 6;
    if ((threadIdx.x & 63) == 0) swsum[wave] = s;
    __syncthreads();
    if (threadIdx.x == 0) {
        float t = 0.f;
        #pragma unroll
        for (int w = 0; w < BLOCK / 64; ++w) t += swsum[w];
        atomicAdd(out, t * (1.0f / NPTS));
    }
}

// ---------------- host ------------------------------------------------------

extern "C" void kernel_launch(void* const* d_in, const int* in_sizes, int n_in,
                              void* d_out, int out_size, void* d_ws, size_t ws_size,
                              hipStream_t stream) {
    const float* x = (const float*)d_in[0];
    const float* y = (const float*)d_in[1];
    float* out = (float*)d_out;

    const size_t need = (size_t)NBATCH * NYC * NPTS * sizeof(float);   // 8 MB

    if (ws_size >= need) {
        float* ws = (float*)d_ws;
        chamfer_part_kernel<<<NBATCH * NXC * NYC, BLOCK, 0, stream>>>(
            x, y, ws, out);
        chamfer_reduce_kernel<<<NBATCH * NPTS / BLOCK, BLOCK, 0, stream>>>(
            ws, out);
    } else {
        unsigned int* ws_min = (unsigned int*)d_ws;
        hipMemsetAsync(out, 0, sizeof(float), stream);
        hipMemsetAsync(ws_min, 0xFF, (size_t)NBATCH * NPTS * sizeof(unsigned int),
                       stream);
        chamfer_min_atomic_kernel<<<NBATCH * NXC * 16, BLOCK, 0, stream>>>(
            x, y, ws_min);
        chamfer_sum_kernel<<<64, BLOCK, 0, stream>>>(ws_min, out);
    }
}